// Round 11
// baseline (31.696 us; speedup 1.0000x reference)
//
#include <hip/hip_runtime.h>

// DynamicMaskHead v11: v10 with the pxw precedence bug fixed
// (blockIdx.x*(16*NT*4)/4 parsed as blockIdx.x*80; must be *320).
// All-MFMA (verified math, absmax 0.046875) + ONE-SHOT LDS param residency:
// Block = 4 waves x 80 px = 320 px; grid = 128 x 4 images x NSPLIT(2)
// = 1024 blocks = exactly 4 blocks/CU; LDS 40960 B/block = exactly
// 160 KiB/CU at 4 blocks. All 8 instances of the block's split are staged
// into LDS once (coalesced, one barrier), then the t-loop is pure
// {5x ds_read_b128 + 25 MFMA + cvt VALU} per instance — no vmcnt, no
// barriers, no L2 latency exposure.
// Per (instance, 16-px tile): 5 MFMAs, zero shuffles:
//   acc0 = ca·coords + W0a·X + W0b·X   (wx,wy,b0 as hi/lo bf16 channels)
//   h0=relu -> a1b MFMA (b1 bias channel) -> h1=relu ->
//   a2r MFMA (row-replicated w2 + b2 bias channel) => acc2[0] IS the output.
// Tiles 0-3: lane group g banks tile g -> one 64-lane coalesced store;
// tile 4: replicated to all groups -> g==0 lanes store 16 px.

#define CIN  64
#define HH   160
#define WW   256
#define HWSZ (HH * WW)
#define PP   1361
#define MASK_BIAS_SHIFT 2.19f
#define PKF  1280              // floats per instance in packed buffer (5120 B)
#define NSPLIT 2               // instance split across gridDim.z
#define NT   5                 // 16-px tiles per wave (80 px)
#define MAXI 8                 // max instances per split (16 / NSPLIT)
#define BLKPX (16 * NT * 4)    // 320 px per block

typedef short short8 __attribute__((ext_vector_type(8)));
typedef float f32x4  __attribute__((ext_vector_type(4)));

union BF8 { short8 s; __bf16 b[8]; };

__device__ inline __bf16 bhi(float v) { return (__bf16)v; }
__device__ inline __bf16 blo(float v) { return (__bf16)(v - (float)(__bf16)v); }

// packed float offsets per instance:
//   0: a00 (W0 x-ch 0..31)   256: a01 (x-ch 32..63)   512: a1b (W1 + b1 ch)
//   768: a2r (replicated w2 + b2 ch)   1024: ca (coord/b0 ch)

__global__ __launch_bounds__(64) void prep_params(
    const float* __restrict__ params, float* __restrict__ pk)
{
    const int t    = blockIdx.x;
    const int lane = threadIdx.x;
    const int col  = lane & 15;
    const int g    = lane >> 4;
    const float* pw = params + (size_t)t * PP;
    float* dst = pk + (size_t)t * PKF;

    const __bf16 z = (__bf16)0.f;

    BF8 a00, a01;
#pragma unroll
    for (int j = 0; j < 8; ++j) {
        a00.b[j] = (__bf16)pw[col * 66 + 2 +      g * 8 + j];
        a01.b[j] = (__bf16)pw[col * 66 + 2 + 32 + g * 8 + j];
    }

    BF8 a1b;                                   // W1 (k=0..15) + b1 bias channel
#pragma unroll
    for (int j = 0; j < 4; ++j)
        a1b.b[j] = (__bf16)pw[1056 + col * 16 + g * 4 + j];
    {
        const float b1 = pw[1344 + col];
        a1b.b[4] = (g == 0) ? bhi(b1) : z;
        a1b.b[5] = (g == 0) ? blo(b1) : z;
        a1b.b[6] = z;  a1b.b[7] = z;
    }

    BF8 a2r;                    // w2 replicated across rows + b2 bias channel
#pragma unroll
    for (int j = 0; j < 4; ++j) a2r.b[j] = (__bf16)pw[1312 + g * 4 + j];
    {
        const float b2 = pw[1360] - MASK_BIAS_SHIFT;
        a2r.b[4] = (g == 0) ? bhi(b2) : z;
        a2r.b[5] = (g == 0) ? blo(b2) : z;
        a2r.b[6] = z;  a2r.b[7] = z;
    }

    BF8 ca;   // [wx_hi,wx_lo,wy_hi,wy_lo,b0_hi,b0_lo,0,0] on g==0 lanes
    {
        const float wx = pw[col * 66 + 0];
        const float wy = pw[col * 66 + 1];
        const float b0 = pw[1328 + col];
        ca.b[0] = (g == 0) ? bhi(wx) : z;
        ca.b[1] = (g == 0) ? blo(wx) : z;
        ca.b[2] = (g == 0) ? bhi(wy) : z;
        ca.b[3] = (g == 0) ? blo(wy) : z;
        ca.b[4] = (g == 0) ? bhi(b0) : z;
        ca.b[5] = (g == 0) ? blo(b0) : z;
        ca.b[6] = z; ca.b[7] = z;
    }

    ((short8*)(dst       ))[lane] = a00.s;
    ((short8*)(dst +  256))[lane] = a01.s;
    ((short8*)(dst +  512))[lane] = a1b.s;
    ((short8*)(dst +  768))[lane] = a2r.s;
    ((short8*)(dst + 1024))[lane] = ca.s;
}

__global__ __launch_bounds__(256, 4) void mask_head_v11(
    const float* __restrict__ x,
    const float* __restrict__ pk,
    const int*   __restrict__ num_ins,
    float*       __restrict__ out,
    int N, int T)
{
    __shared__ __align__(16) float plds[MAXI][PKF];   // 40960 B

    const int tid  = threadIdx.x;
    const int wave = tid >> 6;
    const int lane = tid & 63;
    const int col  = lane & 15;
    const int g    = lane >> 4;
    const int n    = blockIdx.y;
    const int s    = blockIdx.z;
    const int pxw  = blockIdx.x * BLKPX + wave * (16 * NT);   // FIXED: *320

    // instance range for this image (repeat-pad on last image)
    int t0 = 0;
    for (int j = 0; j < n; ++j) t0 += num_ins[j];
    int t1 = t0 + num_ins[n];
    if (n == N - 1) t1 = T;
    if (t1 > T) t1 = T;
    t0 = __builtin_amdgcn_readfirstlane(t0);
    t1 = __builtin_amdgcn_readfirstlane(t1);
    const int M = t1 - t0;

    // instances of this split: t = t0 + s + NSPLIT*i, i in [0, mloc)
    int mloc = (M - s + NSPLIT - 1) / NSPLIT;
    if (mloc < 0) mloc = 0;
    if (mloc > MAXI) mloc = MAXI;

    // ---- one-shot staging: all mloc instances' packed params -> LDS
    for (int c = tid; c < mloc * (PKF / 4); c += 256) {
        const int i   = c / (PKF / 4);
        const int off = c - i * (PKF / 4);
        const int t   = t0 + s + NSPLIT * i;
        ((f32x4*)plds[i])[off] = ((const f32x4*)(pk + (size_t)t * PKF))[off];
    }
    __syncthreads();

    // x fragments: 80 px x 64 ch (40 VGPR), loaded once, reused by all inst
    BF8 xb[NT][2];
    const float* xbase = x + (size_t)n * CIN * HWSZ + pxw + col;
#pragma unroll
    for (int nt = 0; nt < NT; ++nt)
#pragma unroll
        for (int c = 0; c < 2; ++c)
#pragma unroll
            for (int j = 0; j < 8; ++j) {
                const int ch = c * 32 + g * 8 + j;
                xb[nt][c].b[j] = (__bf16)xbase[(size_t)ch * HWSZ + nt * 16];
            }

    // coordinate B-fragments (instance-independent): [xf,xf,yf,yf,1,1,0,0]
    BF8 b2c[NT];
#pragma unroll
    for (int nt = 0; nt < NT; ++nt) {
        const int px = pxw + nt * 16 + col;
        const __bf16 xfb = (__bf16)(float)(px & (WW - 1));
        const __bf16 yfb = (__bf16)(float)(px >> 8);
        b2c[nt].b[0] = xfb; b2c[nt].b[1] = xfb;
        b2c[nt].b[2] = yfb; b2c[nt].b[3] = yfb;
        b2c[nt].b[4] = (__bf16)1.f; b2c[nt].b[5] = (__bf16)1.f;
        b2c[nt].b[6] = (__bf16)0.f; b2c[nt].b[7] = (__bf16)0.f;
    }

    const __bf16 one = (__bf16)1.f, zero = (__bf16)0.f;

    // ---- instance loop: pure LDS + MFMA + VALU (no global, no barriers)
    for (int i = 0; i < mloc; ++i) {
        const int t = t0 + s + NSPLIT * i;
        const short8* fp = (const short8*)plds[i];

        short8 a00 = fp[       lane];
        short8 a01 = fp[ 64 + lane];
        short8 a1b = fp[128 + lane];
        short8 a2r = fp[192 + lane];
        short8 ca  = fp[256 + lane];

        float oval = 0.f, t4 = 0.f;
#pragma unroll
        for (int nt = 0; nt < NT; ++nt) {
            // layer 0: coords/b0 + x-channels in one fp32 accumulator
            f32x4 acc0 = {0.f, 0.f, 0.f, 0.f};
            acc0 = __builtin_amdgcn_mfma_f32_16x16x32_bf16(ca,  b2c[nt].s,   acc0, 0, 0, 0);
            acc0 = __builtin_amdgcn_mfma_f32_16x16x32_bf16(a00, xb[nt][0].s, acc0, 0, 0, 0);
            acc0 = __builtin_amdgcn_mfma_f32_16x16x32_bf16(a01, xb[nt][1].s, acc0, 0, 0, 0);

            BF8 h0;
#pragma unroll
            for (int j = 0; j < 4; ++j) h0.b[j] = (__bf16)fmaxf(acc0[j], 0.f);
            h0.b[4] = one; h0.b[5] = one; h0.b[6] = zero; h0.b[7] = zero;

            // layer 1 (b1 via bias channel)
            f32x4 acc1 = {0.f, 0.f, 0.f, 0.f};
            acc1 = __builtin_amdgcn_mfma_f32_16x16x32_bf16(a1b, h0.s, acc1, 0, 0, 0);

            BF8 h1;
#pragma unroll
            for (int j = 0; j < 4; ++j) h1.b[j] = (__bf16)fmaxf(acc1[j], 0.f);
            h1.b[4] = one; h1.b[5] = one; h1.b[6] = zero; h1.b[7] = zero;

            // layer 2: row-replicated w2 + b2 channel -> acc2[0] is the answer
            f32x4 acc2 = {0.f, 0.f, 0.f, 0.f};
            acc2 = __builtin_amdgcn_mfma_f32_16x16x32_bf16(a2r, h1.s, acc2, 0, 0, 0);

            if (nt == g)  oval = acc2[0];    // tiles 0-3: lane's own tile
            if (nt == 4)  t4   = acc2[0];    // tile 4: replicated to all rows
        }
        float* const op = out + (size_t)t * HWSZ + pxw;
        op[lane] = oval;                      // 64-lane coalesced (tiles 0-3)
        if (g == 0) op[64 + col] = t4;        // 16-lane store (tile 4)
    }
}

// ---- fallback (no workspace): round-2-style kernel, params from global
__global__ __launch_bounds__(256) void mask_head_mfma_nows(
    const float* __restrict__ x,
    const float* __restrict__ params,
    const int*   __restrict__ num_ins,
    float*       __restrict__ out,
    int N, int T)
{
    const int tid  = threadIdx.x;
    const int wave = tid >> 6;
    const int lane = tid & 63;
    const int col  = lane & 15;
    const int g    = lane >> 4;
    const int n    = blockIdx.y;
    const int pxw  = blockIdx.x * 256 + wave * 64;

    int t0 = 0;
    for (int j = 0; j < n; ++j) t0 += num_ins[j];
    int t1 = t0 + num_ins[n];
    if (n == N - 1) t1 = T;
    if (t1 > T) t1 = T;

    BF8 xb[4][2];
    const float* xbase = x + (size_t)n * CIN * HWSZ + pxw + col;
#pragma unroll
    for (int nt = 0; nt < 4; ++nt)
#pragma unroll
        for (int c = 0; c < 2; ++c)
#pragma unroll
            for (int j = 0; j < 8; ++j)
                xb[nt][c].b[j] = (__bf16)xbase[(size_t)(c * 32 + g * 8 + j) * HWSZ + nt * 16];

    float xf[4], yf[4];
#pragma unroll
    for (int nt = 0; nt < 4; ++nt) {
        const int pix = pxw + nt * 16 + col;
        xf[nt] = (float)(pix & (WW - 1));
        yf[nt] = (float)(pix >> 8);
    }

    for (int t = t0; t < t1; ++t) {
        const float* pw = params + (size_t)t * PP;
        BF8 a00, a01, a1;
#pragma unroll
        for (int j = 0; j < 8; ++j) {
            a00.b[j] = (__bf16)pw[col * 66 + 2 +      g * 8 + j];
            a01.b[j] = (__bf16)pw[col * 66 + 2 + 32 + g * 8 + j];
        }
#pragma unroll
        for (int j = 0; j < 4; ++j) {
            a1.b[j]     = (__bf16)pw[1056 + col * 16 + g * 4 + j];
            a1.b[4 + j] = (__bf16)0.f;
        }
        float wxv[4], wyv[4], b0v[4], b1v[4], w2v[4];
#pragma unroll
        for (int j = 0; j < 4; ++j) {
            const int r = g * 4 + j;
            wxv[j] = pw[r * 66 + 0];
            wyv[j] = pw[r * 66 + 1];
            b0v[j] = pw[1328 + r];
            b1v[j] = pw[1344 + r];
            w2v[j] = pw[1312 + r];
        }
        const float b2v = pw[1360] - MASK_BIAS_SHIFT;

        f32x4 acc0[4];
#pragma unroll
        for (int nt = 0; nt < 4; ++nt) {
            f32x4 a = {0.f, 0.f, 0.f, 0.f};
            a = __builtin_amdgcn_mfma_f32_16x16x32_bf16(a00.s, xb[nt][0].s, a, 0, 0, 0);
            a = __builtin_amdgcn_mfma_f32_16x16x32_bf16(a01.s, xb[nt][1].s, a, 0, 0, 0);
            acc0[nt] = a;
        }
        BF8 h0[4];
#pragma unroll
        for (int nt = 0; nt < 4; ++nt)
#pragma unroll
            for (int j = 0; j < 4; ++j) {
                float v = acc0[nt][j] + b0v[j];
                v = fmaf(wxv[j], xf[nt], v);
                v = fmaf(wyv[j], yf[nt], v);
                v = fmaxf(v, 0.f);
                h0[nt].b[j]     = (__bf16)v;
                h0[nt].b[4 + j] = (__bf16)0.f;
            }
        f32x4 acc1[4];
#pragma unroll
        for (int nt = 0; nt < 4; ++nt) {
            f32x4 a = {0.f, 0.f, 0.f, 0.f};
            acc1[nt] = __builtin_amdgcn_mfma_f32_16x16x32_bf16(a1.s, h0[nt].s, a, 0, 0, 0);
        }
        float oval = 0.f;
#pragma unroll
        for (int nt = 0; nt < 4; ++nt) {
            float sum = 0.f;
#pragma unroll
            for (int j = 0; j < 4; ++j) {
                const float h = fmaxf(acc1[nt][j] + b1v[j], 0.f);
                sum = fmaf(w2v[j], h, sum);
            }
            sum += __shfl_xor(sum, 16, 64);
            sum += __shfl_xor(sum, 32, 64);
            if (nt == g) oval = sum + b2v;
        }
        out[(size_t)t * HWSZ + pxw + lane] = oval;
    }
}

extern "C" void kernel_launch(void* const* d_in, const int* in_sizes, int n_in,
                              void* d_out, int out_size, void* d_ws, size_t ws_size,
                              hipStream_t stream) {
    const float* x      = (const float*)d_in[0];
    const float* params = (const float*)d_in[1];
    const int*   nins   = (const int*)d_in[2];
    float*       out    = (float*)d_out;

    const int N = in_sizes[2];            // images
    const int T = in_sizes[1] / PP;       // total instances (param rows)
    const size_t ws_needed = (size_t)T * PKF * sizeof(float);

    if (ws_size >= ws_needed) {
        float* pk = (float*)d_ws;
        prep_params<<<T, dim3(64), 0, stream>>>(params, pk);
        dim3 grid(HWSZ / BLKPX, N, NSPLIT);   // 128 x 4 x 2 = 1024 blocks
        mask_head_v11<<<grid, dim3(256), 0, stream>>>(x, pk, nins, out, N, T);
    } else {
        dim3 grid(HWSZ / 256, N);
        mask_head_mfma_nows<<<grid, dim3(256), 0, stream>>>(x, params, nins, out, N, T);
    }
}

// Round 12
// 31.245 us; speedup vs baseline: 1.0144x; 1.0144x over previous
//
#include <hip/hip_runtime.h>

// DynamicMaskHead v12: v11 (verified, absmax 0.046875) with the instance
// loop rewritten STAGE-WISE for 5-way dependency-chain ILP.
// v11's ablation: zero in-loop global loads changed nothing -> the wall is
// per-wave chain latency (serial 5-stage MFMA chain per tile). Here all 5
// tiles advance together through each stage:
//   S0: 5x MFMA(ca,coords)  S1: 5x MFMA(a00,X0)  S2: 5x MFMA(a01,X1)
//   S3: 5x relu+cvt h       S4: 5x MFMA(a1b,h)   S5: 5x relu+cvt h
//   S6: 5x MFMA(a2r,h)      -> select + store
// acc[5]/h[5] reused across stages (unroll-static indices -> registers);
// a1b/a2r ds_reads deferred to just before their stage to cap live VGPRs.
// Structure otherwise identical to v11: block = 4 waves x 80 px = 320 px,
// one-shot LDS residency of the block's 8 instances (40960 B = 160KiB/CU
// at 4 blocks/CU), grid 128 x 4 x NSPLIT(2) = 1024 blocks.

#define CIN  64
#define HH   160
#define WW   256
#define HWSZ (HH * WW)
#define PP   1361
#define MASK_BIAS_SHIFT 2.19f
#define PKF  1280              // floats per instance in packed buffer (5120 B)
#define NSPLIT 2               // instance split across gridDim.z
#define NT   5                 // 16-px tiles per wave (80 px)
#define MAXI 8                 // max instances per split (16 / NSPLIT)
#define BLKPX (16 * NT * 4)    // 320 px per block

typedef short short8 __attribute__((ext_vector_type(8)));
typedef float f32x4  __attribute__((ext_vector_type(4)));

union BF8 { short8 s; __bf16 b[8]; };

__device__ inline __bf16 bhi(float v) { return (__bf16)v; }
__device__ inline __bf16 blo(float v) { return (__bf16)(v - (float)(__bf16)v); }

// packed float offsets per instance:
//   0: a00 (W0 x-ch 0..31)   256: a01 (x-ch 32..63)   512: a1b (W1 + b1 ch)
//   768: a2r (replicated w2 + b2 ch)   1024: ca (coord/b0 ch)

__global__ __launch_bounds__(64) void prep_params(
    const float* __restrict__ params, float* __restrict__ pk)
{
    const int t    = blockIdx.x;
    const int lane = threadIdx.x;
    const int col  = lane & 15;
    const int g    = lane >> 4;
    const float* pw = params + (size_t)t * PP;
    float* dst = pk + (size_t)t * PKF;

    const __bf16 z = (__bf16)0.f;

    BF8 a00, a01;
#pragma unroll
    for (int j = 0; j < 8; ++j) {
        a00.b[j] = (__bf16)pw[col * 66 + 2 +      g * 8 + j];
        a01.b[j] = (__bf16)pw[col * 66 + 2 + 32 + g * 8 + j];
    }

    BF8 a1b;                                   // W1 (k=0..15) + b1 bias channel
#pragma unroll
    for (int j = 0; j < 4; ++j)
        a1b.b[j] = (__bf16)pw[1056 + col * 16 + g * 4 + j];
    {
        const float b1 = pw[1344 + col];
        a1b.b[4] = (g == 0) ? bhi(b1) : z;
        a1b.b[5] = (g == 0) ? blo(b1) : z;
        a1b.b[6] = z;  a1b.b[7] = z;
    }

    BF8 a2r;                    // w2 replicated across rows + b2 bias channel
#pragma unroll
    for (int j = 0; j < 4; ++j) a2r.b[j] = (__bf16)pw[1312 + g * 4 + j];
    {
        const float b2 = pw[1360] - MASK_BIAS_SHIFT;
        a2r.b[4] = (g == 0) ? bhi(b2) : z;
        a2r.b[5] = (g == 0) ? blo(b2) : z;
        a2r.b[6] = z;  a2r.b[7] = z;
    }

    BF8 ca;   // [wx_hi,wx_lo,wy_hi,wy_lo,b0_hi,b0_lo,0,0] on g==0 lanes
    {
        const float wx = pw[col * 66 + 0];
        const float wy = pw[col * 66 + 1];
        const float b0 = pw[1328 + col];
        ca.b[0] = (g == 0) ? bhi(wx) : z;
        ca.b[1] = (g == 0) ? blo(wx) : z;
        ca.b[2] = (g == 0) ? bhi(wy) : z;
        ca.b[3] = (g == 0) ? blo(wy) : z;
        ca.b[4] = (g == 0) ? bhi(b0) : z;
        ca.b[5] = (g == 0) ? blo(b0) : z;
        ca.b[6] = z; ca.b[7] = z;
    }

    ((short8*)(dst       ))[lane] = a00.s;
    ((short8*)(dst +  256))[lane] = a01.s;
    ((short8*)(dst +  512))[lane] = a1b.s;
    ((short8*)(dst +  768))[lane] = a2r.s;
    ((short8*)(dst + 1024))[lane] = ca.s;
}

__global__ __launch_bounds__(256, 4) void mask_head_v12(
    const float* __restrict__ x,
    const float* __restrict__ pk,
    const int*   __restrict__ num_ins,
    float*       __restrict__ out,
    int N, int T)
{
    __shared__ __align__(16) float plds[MAXI][PKF];   // 40960 B

    const int tid  = threadIdx.x;
    const int wave = tid >> 6;
    const int lane = tid & 63;
    const int col  = lane & 15;
    const int g    = lane >> 4;
    const int n    = blockIdx.y;
    const int s    = blockIdx.z;
    const int pxw  = blockIdx.x * BLKPX + wave * (16 * NT);

    // instance range for this image (repeat-pad on last image)
    int t0 = 0;
    for (int j = 0; j < n; ++j) t0 += num_ins[j];
    int t1 = t0 + num_ins[n];
    if (n == N - 1) t1 = T;
    if (t1 > T) t1 = T;
    t0 = __builtin_amdgcn_readfirstlane(t0);
    t1 = __builtin_amdgcn_readfirstlane(t1);
    const int M = t1 - t0;

    // instances of this split: t = t0 + s + NSPLIT*i, i in [0, mloc)
    int mloc = (M - s + NSPLIT - 1) / NSPLIT;
    if (mloc < 0) mloc = 0;
    if (mloc > MAXI) mloc = MAXI;

    // ---- one-shot staging: all mloc instances' packed params -> LDS
    for (int c = tid; c < mloc * (PKF / 4); c += 256) {
        const int i   = c / (PKF / 4);
        const int off = c - i * (PKF / 4);
        const int t   = t0 + s + NSPLIT * i;
        ((f32x4*)plds[i])[off] = ((const f32x4*)(pk + (size_t)t * PKF))[off];
    }
    __syncthreads();

    // x fragments: 80 px x 64 ch (40 VGPR), loaded once, reused by all inst
    BF8 xb[NT][2];
    const float* xbase = x + (size_t)n * CIN * HWSZ + pxw + col;
#pragma unroll
    for (int nt = 0; nt < NT; ++nt)
#pragma unroll
        for (int c = 0; c < 2; ++c)
#pragma unroll
            for (int j = 0; j < 8; ++j) {
                const int ch = c * 32 + g * 8 + j;
                xb[nt][c].b[j] = (__bf16)xbase[(size_t)ch * HWSZ + nt * 16];
            }

    // coordinate B-fragments (instance-independent): [xf,xf,yf,yf,1,1,0,0]
    BF8 b2c[NT];
#pragma unroll
    for (int nt = 0; nt < NT; ++nt) {
        const int px = pxw + nt * 16 + col;
        const __bf16 xfb = (__bf16)(float)(px & (WW - 1));
        const __bf16 yfb = (__bf16)(float)(px >> 8);
        b2c[nt].b[0] = xfb; b2c[nt].b[1] = xfb;
        b2c[nt].b[2] = yfb; b2c[nt].b[3] = yfb;
        b2c[nt].b[4] = (__bf16)1.f; b2c[nt].b[5] = (__bf16)1.f;
        b2c[nt].b[6] = (__bf16)0.f; b2c[nt].b[7] = (__bf16)0.f;
    }

    const __bf16 one = (__bf16)1.f, zero = (__bf16)0.f;

    // ---- instance loop: stage-wise across all 5 tiles (5-way chain ILP)
    for (int i = 0; i < mloc; ++i) {
        const int t = t0 + s + NSPLIT * i;
        const short8* fp = (const short8*)plds[i];

        short8 ca  = fp[256 + lane];
        short8 a00 = fp[       lane];
        short8 a01 = fp[ 64 + lane];

        f32x4 acc[NT];
        // S0: coordinate/bias channels
#pragma unroll
        for (int nt = 0; nt < NT; ++nt) {
            f32x4 z4 = {0.f, 0.f, 0.f, 0.f};
            acc[nt] = __builtin_amdgcn_mfma_f32_16x16x32_bf16(ca, b2c[nt].s, z4, 0, 0, 0);
        }
        // S1/S2: x channels
#pragma unroll
        for (int nt = 0; nt < NT; ++nt)
            acc[nt] = __builtin_amdgcn_mfma_f32_16x16x32_bf16(a00, xb[nt][0].s, acc[nt], 0, 0, 0);
#pragma unroll
        for (int nt = 0; nt < NT; ++nt)
            acc[nt] = __builtin_amdgcn_mfma_f32_16x16x32_bf16(a01, xb[nt][1].s, acc[nt], 0, 0, 0);

        // S3: relu + cvt -> h (with layer1 bias channel pair = 1)
        BF8 h[NT];
#pragma unroll
        for (int nt = 0; nt < NT; ++nt) {
#pragma unroll
            for (int j = 0; j < 4; ++j) h[nt].b[j] = (__bf16)fmaxf(acc[nt][j], 0.f);
            h[nt].b[4] = one; h[nt].b[5] = one; h[nt].b[6] = zero; h[nt].b[7] = zero;
        }

        // S4: layer 1 (b1 via bias channel); a1b read deferred to here
        short8 a1b = fp[128 + lane];
#pragma unroll
        for (int nt = 0; nt < NT; ++nt) {
            f32x4 z4 = {0.f, 0.f, 0.f, 0.f};
            acc[nt] = __builtin_amdgcn_mfma_f32_16x16x32_bf16(a1b, h[nt].s, z4, 0, 0, 0);
        }

        // S5: relu + cvt -> h (with layer2 bias channel pair = 1)
#pragma unroll
        for (int nt = 0; nt < NT; ++nt) {
#pragma unroll
            for (int j = 0; j < 4; ++j) h[nt].b[j] = (__bf16)fmaxf(acc[nt][j], 0.f);
            h[nt].b[4] = one; h[nt].b[5] = one; h[nt].b[6] = zero; h[nt].b[7] = zero;
        }

        // S6: layer 2 (row-replicated w2 + b2 channel); a2r read deferred
        short8 a2r = fp[192 + lane];
#pragma unroll
        for (int nt = 0; nt < NT; ++nt) {
            f32x4 z4 = {0.f, 0.f, 0.f, 0.f};
            acc[nt] = __builtin_amdgcn_mfma_f32_16x16x32_bf16(a2r, h[nt].s, z4, 0, 0, 0);
        }

        // select + store: tiles 0-3 -> lane group g; tile 4 -> g==0 lanes
        float oval = 0.f, t4 = 0.f;
#pragma unroll
        for (int nt = 0; nt < NT; ++nt) {
            if (nt == g)  oval = acc[nt][0];
            if (nt == 4)  t4   = acc[nt][0];
        }
        float* const op = out + (size_t)t * HWSZ + pxw;
        op[lane] = oval;                      // 64-lane coalesced (tiles 0-3)
        if (g == 0) op[64 + col] = t4;        // 16-lane store (tile 4)
    }
}

// ---- fallback (no workspace): round-2-style kernel, params from global
__global__ __launch_bounds__(256) void mask_head_mfma_nows(
    const float* __restrict__ x,
    const float* __restrict__ params,
    const int*   __restrict__ num_ins,
    float*       __restrict__ out,
    int N, int T)
{
    const int tid  = threadIdx.x;
    const int wave = tid >> 6;
    const int lane = tid & 63;
    const int col  = lane & 15;
    const int g    = lane >> 4;
    const int n    = blockIdx.y;
    const int pxw  = blockIdx.x * 256 + wave * 64;

    int t0 = 0;
    for (int j = 0; j < n; ++j) t0 += num_ins[j];
    int t1 = t0 + num_ins[n];
    if (n == N - 1) t1 = T;
    if (t1 > T) t1 = T;

    BF8 xb[4][2];
    const float* xbase = x + (size_t)n * CIN * HWSZ + pxw + col;
#pragma unroll
    for (int nt = 0; nt < 4; ++nt)
#pragma unroll
        for (int c = 0; c < 2; ++c)
#pragma unroll
            for (int j = 0; j < 8; ++j)
                xb[nt][c].b[j] = (__bf16)xbase[(size_t)(c * 32 + g * 8 + j) * HWSZ + nt * 16];

    float xf[4], yf[4];
#pragma unroll
    for (int nt = 0; nt < 4; ++nt) {
        const int pix = pxw + nt * 16 + col;
        xf[nt] = (float)(pix & (WW - 1));
        yf[nt] = (float)(pix >> 8);
    }

    for (int t = t0; t < t1; ++t) {
        const float* pw = params + (size_t)t * PP;
        BF8 a00, a01, a1;
#pragma unroll
        for (int j = 0; j < 8; ++j) {
            a00.b[j] = (__bf16)pw[col * 66 + 2 +      g * 8 + j];
            a01.b[j] = (__bf16)pw[col * 66 + 2 + 32 + g * 8 + j];
        }
#pragma unroll
        for (int j = 0; j < 4; ++j) {
            a1.b[j]     = (__bf16)pw[1056 + col * 16 + g * 4 + j];
            a1.b[4 + j] = (__bf16)0.f;
        }
        float wxv[4], wyv[4], b0v[4], b1v[4], w2v[4];
#pragma unroll
        for (int j = 0; j < 4; ++j) {
            const int r = g * 4 + j;
            wxv[j] = pw[r * 66 + 0];
            wyv[j] = pw[r * 66 + 1];
            b0v[j] = pw[1328 + r];
            b1v[j] = pw[1344 + r];
            w2v[j] = pw[1312 + r];
        }
        const float b2v = pw[1360] - MASK_BIAS_SHIFT;

        f32x4 acc0[4];
#pragma unroll
        for (int nt = 0; nt < 4; ++nt) {
            f32x4 a = {0.f, 0.f, 0.f, 0.f};
            a = __builtin_amdgcn_mfma_f32_16x16x32_bf16(a00.s, xb[nt][0].s, a, 0, 0, 0);
            a = __builtin_amdgcn_mfma_f32_16x16x32_bf16(a01.s, xb[nt][1].s, a, 0, 0, 0);
            acc0[nt] = a;
        }
        BF8 h0[4];
#pragma unroll
        for (int nt = 0; nt < 4; ++nt)
#pragma unroll
            for (int j = 0; j < 4; ++j) {
                float v = acc0[nt][j] + b0v[j];
                v = fmaf(wxv[j], xf[nt], v);
                v = fmaf(wyv[j], yf[nt], v);
                v = fmaxf(v, 0.f);
                h0[nt].b[j]     = (__bf16)v;
                h0[nt].b[4 + j] = (__bf16)0.f;
            }
        f32x4 acc1[4];
#pragma unroll
        for (int nt = 0; nt < 4; ++nt) {
            f32x4 a = {0.f, 0.f, 0.f, 0.f};
            acc1[nt] = __builtin_amdgcn_mfma_f32_16x16x32_bf16(a1.s, h0[nt].s, a, 0, 0, 0);
        }
        float oval = 0.f;
#pragma unroll
        for (int nt = 0; nt < 4; ++nt) {
            float sum = 0.f;
#pragma unroll
            for (int j = 0; j < 4; ++j) {
                const float h = fmaxf(acc1[nt][j] + b1v[j], 0.f);
                sum = fmaf(w2v[j], h, sum);
            }
            sum += __shfl_xor(sum, 16, 64);
            sum += __shfl_xor(sum, 32, 64);
            if (nt == g) oval = sum + b2v;
        }
        out[(size_t)t * HWSZ + pxw + lane] = oval;
    }
}

extern "C" void kernel_launch(void* const* d_in, const int* in_sizes, int n_in,
                              void* d_out, int out_size, void* d_ws, size_t ws_size,
                              hipStream_t stream) {
    const float* x      = (const float*)d_in[0];
    const float* params = (const float*)d_in[1];
    const int*   nins   = (const int*)d_in[2];
    float*       out    = (float*)d_out;

    const int N = in_sizes[2];            // images
    const int T = in_sizes[1] / PP;       // total instances (param rows)
    const size_t ws_needed = (size_t)T * PKF * sizeof(float);

    if (ws_size >= ws_needed) {
        float* pk = (float*)d_ws;
        prep_params<<<T, dim3(64), 0, stream>>>(params, pk);
        dim3 grid(HWSZ / BLKPX, N, NSPLIT);   // 128 x 4 x 2 = 1024 blocks
        mask_head_v12<<<grid, dim3(256), 0, stream>>>(x, pk, nins, out, N, T);
    } else {
        dim3 grid(HWSZ / 256, N);
        mask_head_mfma_nows<<<grid, dim3(256), 0, stream>>>(x, params, nins, out, N, T);
    }
}